// Round 1
// baseline (564.891 us; speedup 1.0000x reference)
//
#include <hip/hip_runtime.h>
#include <cstddef>
#include <cstdint>

#define LRELU(v) ((v) > 0.f ? (v) : 0.2f * (v))

// ================= K1: fused gemm1 + fold(W2,a2) + deg-init =================
// blocks [0,GB): h1 = x@W1 (+as1/ad1);  [GB,GB+64): wfold;  rest: deg[i]=1.

__global__ __launch_bounds__(256) void k_front(const float* __restrict__ x,
                                               const float* __restrict__ W1,
                                               const float* __restrict__ a_src1,
                                               const float* __restrict__ a_dst1,
                                               const float* __restrict__ W2,
                                               const float* __restrict__ a_src2,
                                               const float* __restrict__ a_dst2,
                                               float* h1, float* as1, float* ad1,
                                               float* wfold, int* deg, int N, int GB) {
    int t = threadIdx.x;
    int b = blockIdx.x;
    if (b < GB) {
        // ---- gemm1: 16 nodes/block, 4 waves, wave owns 4 nodes, lane = column ----
        __shared__ float xs[16][128];
        int n0 = b * 16;
#pragma unroll
        for (int i = 0; i < 2; i++) {
            int idx = (t + i * 256) * 4;
            int r = idx >> 7, c = idx & 127;
            int n = n0 + r;
            float4 v = make_float4(0.f, 0.f, 0.f, 0.f);
            if (n < N) v = *(const float4*)&x[(size_t)n * 128 + c];
            *(float4*)&xs[r][c] = v;
        }
        __syncthreads();
        int wv = t >> 6, lane = t & 63;
        int m0 = wv * 4;
        float acc[4] = {0.f, 0.f, 0.f, 0.f};
        for (int k0 = 0; k0 < 128; k0 += 4) {
            float w0 = W1[(k0 + 0) * 64 + lane];
            float w1 = W1[(k0 + 1) * 64 + lane];
            float w2 = W1[(k0 + 2) * 64 + lane];
            float w3 = W1[(k0 + 3) * 64 + lane];
#pragma unroll
            for (int mi = 0; mi < 4; mi++) {
                float4 a = *(const float4*)&xs[m0 + mi][k0];
                acc[mi] += a.x * w0 + a.y * w1 + a.z * w2 + a.w * w3;
            }
        }
        float was = a_src1[lane], wad = a_dst1[lane];
#pragma unroll
        for (int mi = 0; mi < 4; mi++) {
            int n = n0 + m0 + mi;
            if (n >= N) break;
            h1[(size_t)n * 64 + lane] = acc[mi];
            float ps = acc[mi] * was, pd = acc[mi] * wad;
            ps += __shfl_xor(ps, 1); ps += __shfl_xor(ps, 2); ps += __shfl_xor(ps, 4);
            pd += __shfl_xor(pd, 1); pd += __shfl_xor(pd, 2); pd += __shfl_xor(pd, 4);
            if ((lane & 7) == 0) {
                as1[n * 8 + (lane >> 3)] = ps;
                ad1[n * 8 + (lane >> 3)] = pd;
            }
        }
    } else if (b < GB + 64) {
        // ---- fold: block per k-row of W2; coalesced float4; 32-lane head groups ----
        int k = b - GB;
        int c0 = t * 4;
        int h = t >> 5;
        float4 w = *(const float4*)&W2[(size_t)k * 1024 + c0];
        float4 s4 = *(const float4*)&a_src2[c0];
        float4 d4 = *(const float4*)&a_dst2[c0];
        float ss = w.x * s4.x + w.y * s4.y + w.z * s4.z + w.w * s4.w;
        float sd = w.x * d4.x + w.y * d4.y + w.z * d4.z + w.w * d4.w;
#pragma unroll
        for (int off = 1; off <= 16; off <<= 1) {
            ss += __shfl_xor(ss, off);
            sd += __shfl_xor(sd, off);
        }
        if ((t & 31) == 0) {
            wfold[k * 8 + h] = ss;
            wfold[512 + k * 8 + h] = sd;
        }
    } else {
        int i = (b - GB - 64) * 256 + t;
        if (i < N) deg[i] = 1;  // self-loop
    }
}

// ================= CSR build =================

__global__ void k_hist(const int* src, const int* dst, int* deg, int E) {
    int e = blockIdx.x * blockDim.x + threadIdx.x;
    if (e < E) {
        int s = src[e], d = dst[e];
        if (s != d) atomicAdd(&deg[d], 1);
    }
}

__global__ __launch_bounds__(1024) void k_scan(const int* deg, int* offs, int* cursor, int N) {
    __shared__ int part[1024];
    int t = threadIdx.x;
    int chunk = (N + 1023) >> 10;
    int start = t * chunk;
    int s = 0;
    for (int i = 0; i < chunk; i++) {
        int idx = start + i;
        if (idx < N) s += deg[idx];
    }
    part[t] = s;
    __syncthreads();
    for (int off = 1; off < 1024; off <<= 1) {
        int v = (t >= off) ? part[t - off] : 0;
        __syncthreads();
        part[t] += v;
        __syncthreads();
    }
    int run = part[t] - s;
    for (int i = 0; i < chunk; i++) {
        int idx = start + i;
        if (idx < N) {
            offs[idx] = run;
            cursor[idx] = run;
            run += deg[idx];
        }
    }
    if (t == 1023) offs[N] = part[1023];
}

__global__ void k_fill(const int* src, const int* dst, int* cursor, int* csr, int E, int N) {
    int e = blockIdx.x * blockDim.x + threadIdx.x;
    if (e < E) {
        int s = src[e], d = dst[e];
        if (s != d) {
            int pos = atomicAdd(&cursor[d], 1);
            csr[pos] = s;
        }
    } else if (e < E + N) {
        int i = e - E;
        int pos = atomicAdd(&cursor[i], 1);
        csr[pos] = i;
    }
}

// ================= fused attention+aggregation, layer 1 =================
// One wave per dst node. Phase A: online-softmax alpha into per-wave LDS.
// Phase B: aggregate h1, bias+ELU -> z, then wfold dot -> as2/ad2.

__global__ __launch_bounds__(256) void k_attn1(const int* offs, const int* csr,
                                               const float* __restrict__ h1,
                                               const float* __restrict__ as1,
                                               const float* __restrict__ ad1,
                                               const float* __restrict__ b1,
                                               const float* __restrict__ wfold,
                                               float* z, float* as2, float* ad2, int N) {
    __shared__ float al[4][512];  // 64 edges x 8 heads per wave
    __shared__ int   sc[4][64];
    __shared__ float zr[4][64];
    int w = threadIdx.x >> 6, lane = threadIdx.x & 63;
    int node = blockIdx.x * 4 + w;
    if (node >= N) return;
    int el = lane >> 3, h = lane & 7;
    int beg = offs[node], end = offs[node + 1];
    int deg = end - beg;
    float adv = ad1[node * 8 + h];
    float m = -1e30f, l = 0.f;
    for (int it = 0; it * 8 < deg; it++) {
        int j = beg + it * 8 + el;
        float e = -1e30f;
        int s = 0;
        if (j < end) {
            s = csr[j];
            float v = as1[s * 8 + h] + adv;
            e = LRELU(v);
        }
        if (it < 8) {
            al[w][it * 64 + lane] = e;  // linear: no bank conflicts
            if (h == 0 && j < end) sc[w][it * 8 + el] = s;
        }
        float nm = fmaxf(m, e);
        l = l * __expf(m - nm) + ((j < end) ? __expf(e - nm) : 0.f);
        m = nm;
    }
#pragma unroll
    for (int off = 8; off < 64; off <<= 1) {
        float m2 = __shfl_xor(m, off), l2 = __shfl_xor(l, off);
        float nm = fmaxf(m, m2);
        l = l * __expf(m - nm) + l2 * __expf(m2 - nm);
        m = nm;
    }
    float inv = 1.f / (l + 1e-16f);
    for (int it = 0; it < 8 && it * 8 < deg; it++) {
        int idx = it * 64 + lane;
        al[w][idx] = __expf(al[w][idx] - m) * inv;
    }
    // ---- phase B: lane = channel, head hb ----
    int hb = lane >> 3;
    float mB   = __shfl(m, hb);
    float invB = __shfl(inv, hb);
    float advB = __shfl(adv, hb);
    float acc = 0.f;
    for (int j = beg; j < end; j++) {
        int e0 = j - beg;
        float a;
        int s;
        if (e0 < 64) {
            a = al[w][e0 * 8 + hb];
            s = sc[w][e0];
        } else {  // overflow: recompute (deg>64 is rare)
            s = csr[j];
            float v = as1[s * 8 + hb] + advB;
            a = __expf(LRELU(v) - mB) * invB;
        }
        acc += a * h1[(size_t)s * 64 + lane];
    }
    float val = acc + b1[lane];
    float zv = val > 0.f ? val : __expf(val) - 1.f;  // ELU
    z[(size_t)node * 64 + lane] = zv;
    zr[w][lane] = zv;
    if (lane < 16) {
        int hh = lane & 7;
        const float* wf = wfold + (lane < 8 ? 0 : 512);
        float sdot = 0.f;
        for (int k = 0; k < 64; k++) sdot += zr[w][k] * wf[k * 8 + hh];
        if (lane < 8) as2[node * 8 + hh] = sdot;
        else          ad2[node * 8 + hh] = sdot;
    }
}

// ================= fused attention+aggregation+GEMM+log_softmax, layer 2 =================
// 8 nodes/block, 512 threads. Wave w: attention for node w -> acc[8 heads] per lane(=ch).
// acc rows dropped into LDS (reusing the alpha buffer), then wave w computes head w's
// 128 output columns for all 8 nodes (LDS reads are wave-uniform broadcasts), followed
// by cross-wave log_softmax. Eliminates the agg[N,8,64] HBM round-trip entirely.

__global__ __launch_bounds__(512) void k_attn2_out(const int* offs, const int* csr,
                                                   const float* __restrict__ zt,
                                                   const float* __restrict__ as2,
                                                   const float* __restrict__ ad2,
                                                   const float* __restrict__ W2,
                                                   const float* __restrict__ b2,
                                                   float* out, int N) {
    __shared__ float al[8][512];   // alpha buffer, later reused as agg rows [node][head*64+k]
    __shared__ int   sc[8][64];
    __shared__ float red[8][8];
    int w = threadIdx.x >> 6, lane = threadIdx.x & 63;
    int node = blockIdx.x * 8 + w;
    bool active = node < N;
    int el = lane >> 3, h = lane & 7;
    int beg = 0, end = 0;
    if (active) { beg = offs[node]; end = offs[node + 1]; }
    int deg = end - beg;
    float adv = active ? ad2[node * 8 + h] : 0.f;
    float m = -1e30f, l = 0.f;
    for (int it = 0; it * 8 < deg; it++) {
        int j = beg + it * 8 + el;
        float e = -1e30f;
        int s = 0;
        if (j < end) {
            s = csr[j];
            float v = as2[s * 8 + h] + adv;
            e = LRELU(v);
        }
        if (it < 8) {
            al[w][it * 64 + lane] = e;
            if (h == 0 && j < end) sc[w][it * 8 + el] = s;
        }
        float nm = fmaxf(m, e);
        l = l * __expf(m - nm) + ((j < end) ? __expf(e - nm) : 0.f);
        m = nm;
    }
#pragma unroll
    for (int off = 8; off < 64; off <<= 1) {
        float m2 = __shfl_xor(m, off), l2 = __shfl_xor(l, off);
        float nm = fmaxf(m, m2);
        l = l * __expf(m - nm) + l2 * __expf(m2 - nm);
        m = nm;
    }
    float inv = 1.f / (l + 1e-16f);
    for (int it = 0; it < 8 && it * 8 < deg; it++) {
        int idx = it * 64 + lane;
        al[w][idx] = __expf(al[w][idx] - m) * inv;
    }
    float mH[8], invH[8], advH[8];
#pragma unroll
    for (int hh = 0; hh < 8; hh++) {
        mH[hh] = __shfl(m, hh);
        invH[hh] = __shfl(inv, hh);
        advH[hh] = __shfl(adv, hh);
    }
    float acc[8] = {0.f, 0.f, 0.f, 0.f, 0.f, 0.f, 0.f, 0.f};
    for (int j = beg; j < end; j++) {
        int e0 = j - beg;
        float a[8];
        int s;
        if (e0 < 64) {
            float4 a0 = *(const float4*)&al[w][e0 * 8];
            float4 a1 = *(const float4*)&al[w][e0 * 8 + 4];
            a[0] = a0.x; a[1] = a0.y; a[2] = a0.z; a[3] = a0.w;
            a[4] = a1.x; a[5] = a1.y; a[6] = a1.z; a[7] = a1.w;
            s = sc[w][e0];
        } else {
            s = csr[j];
#pragma unroll
            for (int hh = 0; hh < 8; hh++) {
                float v = as2[s * 8 + hh] + advH[hh];
                a[hh] = __expf(LRELU(v) - mH[hh]) * invH[hh];
            }
        }
        float zvv = zt[(size_t)s * 64 + lane];
#pragma unroll
        for (int hh = 0; hh < 8; hh++) acc[hh] += a[hh] * zvv;
    }
    // ---- drop agg row into LDS (safe: al[w] reads are done; per-wave in-order) ----
#pragma unroll
    for (int hh = 0; hh < 8; hh++) al[w][hh * 64 + lane] = acc[hh];
    __syncthreads();
    // ---- per-head GEMM: wave w = head w, lane owns 2 columns, all 8 nodes ----
    int c = w * 128 + lane * 2;
    float2 bb = *(const float2*)&b2[c];
    float2 o[8];
#pragma unroll
    for (int mi = 0; mi < 8; mi++) o[mi] = bb;
    for (int k0 = 0; k0 < 64; k0 += 4) {
        float2 w0 = *(const float2*)&W2[(size_t)(k0 + 0) * 1024 + c];
        float2 w1 = *(const float2*)&W2[(size_t)(k0 + 1) * 1024 + c];
        float2 w2 = *(const float2*)&W2[(size_t)(k0 + 2) * 1024 + c];
        float2 w3 = *(const float2*)&W2[(size_t)(k0 + 3) * 1024 + c];
#pragma unroll
        for (int mi = 0; mi < 8; mi++) {
            float4 a = *(const float4*)&al[mi][w * 64 + k0];  // wave-uniform broadcast
            o[mi].x += a.x * w0.x + a.y * w1.x + a.z * w2.x + a.w * w3.x;
            o[mi].y += a.x * w0.y + a.y * w1.y + a.z * w2.y + a.w * w3.y;
        }
    }
    // ---- log_softmax across the full 1024 columns (8 waves x 128 cols) ----
    float gmax[8], logZ[8];
#pragma unroll
    for (int mi = 0; mi < 8; mi++) {
        float v = fmaxf(o[mi].x, o[mi].y);
#pragma unroll
        for (int off = 32; off; off >>= 1) v = fmaxf(v, __shfl_xor(v, off));
        if (lane == 0) red[w][mi] = v;
    }
    __syncthreads();
#pragma unroll
    for (int mi = 0; mi < 8; mi++) {
        float g = red[0][mi];
#pragma unroll
        for (int ww = 1; ww < 8; ww++) g = fmaxf(g, red[ww][mi]);
        gmax[mi] = g;
    }
    __syncthreads();
#pragma unroll
    for (int mi = 0; mi < 8; mi++) {
        float v = __expf(o[mi].x - gmax[mi]) + __expf(o[mi].y - gmax[mi]);
#pragma unroll
        for (int off = 32; off; off >>= 1) v += __shfl_xor(v, off);
        if (lane == 0) red[w][mi] = v;
    }
    __syncthreads();
#pragma unroll
    for (int mi = 0; mi < 8; mi++) {
        float gs = red[0][mi];
#pragma unroll
        for (int ww = 1; ww < 8; ww++) gs += red[ww][mi];
        logZ[mi] = gmax[mi] + __logf(gs);
    }
#pragma unroll
    for (int mi = 0; mi < 8; mi++) {
        int n = blockIdx.x * 8 + mi;
        if (n >= N) continue;
        float2 ov = make_float2(o[mi].x - logZ[mi], o[mi].y - logZ[mi]);
        *(float2*)&out[(size_t)n * 1024 + c] = ov;
    }
}

// ================= launch =================

extern "C" void kernel_launch(void* const* d_in, const int* in_sizes, int n_in,
                              void* d_out, int out_size, void* d_ws, size_t ws_size,
                              hipStream_t stream) {
    const float* x      = (const float*)d_in[0];
    const int*   ei     = (const int*)d_in[1];
    const float* W1     = (const float*)d_in[2];
    const float* a_src1 = (const float*)d_in[3];
    const float* a_dst1 = (const float*)d_in[4];
    const float* b1     = (const float*)d_in[5];
    const float* W2     = (const float*)d_in[6];
    const float* a_src2 = (const float*)d_in[7];
    const float* a_dst2 = (const float*)d_in[8];
    const float* b2     = (const float*)d_in[9];
    float* out = (float*)d_out;

    int N = in_sizes[0] / 128;
    int E = in_sizes[1] / 2;
    const int* src = ei;
    const int* dst = ei + E;

    char* p = (char*)d_ws;
    auto carve = [&](size_t bytes) {
        void* r = (void*)p;
        p += (bytes + 255) & ~(size_t)255;
        return r;
    };
    int*   deg    = (int*)carve((size_t)N * 4);
    int*   offs   = (int*)carve((size_t)(N + 1) * 4);
    int*   cursor = (int*)carve((size_t)N * 4);
    int*   csr    = (int*)carve((size_t)(E + N) * 4);
    float* h1     = (float*)carve((size_t)N * 64 * 4);
    float* as1    = (float*)carve((size_t)N * 8 * 4);
    float* ad1    = (float*)carve((size_t)N * 8 * 4);
    float* z      = (float*)carve((size_t)N * 64 * 4);
    float* as2    = (float*)carve((size_t)N * 8 * 4);
    float* ad2    = (float*)carve((size_t)N * 8 * 4);
    float* wfold  = (float*)carve((size_t)1024 * 4);

    int GB = (N + 15) / 16;                 // gemm1 blocks
    int DB = (N + 255) / 256;               // deg-init blocks
    int nb4 = (N + 3) / 4;

    // K1: gemm1 + fold + deg-init (independent work, one dispatch)
    k_front<<<GB + 64 + DB, 256, 0, stream>>>(x, W1, a_src1, a_dst1, W2, a_src2, a_dst2,
                                              h1, as1, ad1, wfold, deg, N, GB);
    // CSR build
    k_hist<<<(E + 255) / 256, 256, 0, stream>>>(src, dst, deg, E);
    k_scan<<<1, 1024, 0, stream>>>(deg, offs, cursor, N);
    k_fill<<<(E + N + 255) / 256, 256, 0, stream>>>(src, dst, cursor, csr, E, N);
    // layer 1 (fused alpha+agg)
    k_attn1<<<nb4, 256, 0, stream>>>(offs, csr, h1, as1, ad1, b1, wfold, z, as2, ad2, N);
    // layer 2 (fused alpha+agg+per-head GEMM+log_softmax) — no agg round-trip
    k_attn2_out<<<(N + 7) / 8, 512, 0, stream>>>(offs, csr, z, as2, ad2, W2, b2, out, N);
}

// Round 2
// 394.481 us; speedup vs baseline: 1.4320x; 1.4320x over previous
//
#include <hip/hip_runtime.h>
#include <cstddef>
#include <cstdint>

#define LRELU(v) ((v) > 0.f ? (v) : 0.2f * (v))

// ================= K1: fused gemm1 + fold(W2,a2) + deg-init =================
// blocks [0,GB): h1 = x@W1 (+as1/ad1);  [GB,GB+64): wfold;  rest: deg[i]=1.

__global__ __launch_bounds__(256) void k_front(const float* __restrict__ x,
                                               const float* __restrict__ W1,
                                               const float* __restrict__ a_src1,
                                               const float* __restrict__ a_dst1,
                                               const float* __restrict__ W2,
                                               const float* __restrict__ a_src2,
                                               const float* __restrict__ a_dst2,
                                               float* h1, float* as1, float* ad1,
                                               float* wfold, int* deg, int N, int GB) {
    int t = threadIdx.x;
    int b = blockIdx.x;
    if (b < GB) {
        // ---- gemm1: 16 nodes/block, 4 waves, wave owns 4 nodes, lane = column ----
        __shared__ float xs[16][128];
        int n0 = b * 16;
#pragma unroll
        for (int i = 0; i < 2; i++) {
            int idx = (t + i * 256) * 4;
            int r = idx >> 7, c = idx & 127;
            int n = n0 + r;
            float4 v = make_float4(0.f, 0.f, 0.f, 0.f);
            if (n < N) v = *(const float4*)&x[(size_t)n * 128 + c];
            *(float4*)&xs[r][c] = v;
        }
        __syncthreads();
        int wv = t >> 6, lane = t & 63;
        int m0 = wv * 4;
        float acc[4] = {0.f, 0.f, 0.f, 0.f};
        for (int k0 = 0; k0 < 128; k0 += 4) {
            float w0 = W1[(k0 + 0) * 64 + lane];
            float w1 = W1[(k0 + 1) * 64 + lane];
            float w2 = W1[(k0 + 2) * 64 + lane];
            float w3 = W1[(k0 + 3) * 64 + lane];
#pragma unroll
            for (int mi = 0; mi < 4; mi++) {
                float4 a = *(const float4*)&xs[m0 + mi][k0];
                acc[mi] += a.x * w0 + a.y * w1 + a.z * w2 + a.w * w3;
            }
        }
        float was = a_src1[lane], wad = a_dst1[lane];
#pragma unroll
        for (int mi = 0; mi < 4; mi++) {
            int n = n0 + m0 + mi;
            if (n >= N) break;
            h1[(size_t)n * 64 + lane] = acc[mi];
            float ps = acc[mi] * was, pd = acc[mi] * wad;
            ps += __shfl_xor(ps, 1); ps += __shfl_xor(ps, 2); ps += __shfl_xor(ps, 4);
            pd += __shfl_xor(pd, 1); pd += __shfl_xor(pd, 2); pd += __shfl_xor(pd, 4);
            if ((lane & 7) == 0) {
                as1[n * 8 + (lane >> 3)] = ps;
                ad1[n * 8 + (lane >> 3)] = pd;
            }
        }
    } else if (b < GB + 64) {
        // ---- fold: block per k-row of W2; coalesced float4; 32-lane head groups ----
        int k = b - GB;
        int c0 = t * 4;
        int h = t >> 5;
        float4 w = *(const float4*)&W2[(size_t)k * 1024 + c0];
        float4 s4 = *(const float4*)&a_src2[c0];
        float4 d4 = *(const float4*)&a_dst2[c0];
        float ss = w.x * s4.x + w.y * s4.y + w.z * s4.z + w.w * s4.w;
        float sd = w.x * d4.x + w.y * d4.y + w.z * d4.z + w.w * d4.w;
#pragma unroll
        for (int off = 1; off <= 16; off <<= 1) {
            ss += __shfl_xor(ss, off);
            sd += __shfl_xor(sd, off);
        }
        if ((t & 31) == 0) {
            wfold[k * 8 + h] = ss;
            wfold[512 + k * 8 + h] = sd;
        }
    } else {
        int i = (b - GB - 64) * 256 + t;
        if (i < N) deg[i] = 1;  // self-loop
    }
}

// ================= CSR build =================

__global__ void k_hist(const int* src, const int* dst, int* deg, int E) {
    int e = blockIdx.x * blockDim.x + threadIdx.x;
    if (e < E) {
        int s = src[e], d = dst[e];
        if (s != d) atomicAdd(&deg[d], 1);
    }
}

__global__ __launch_bounds__(1024) void k_scan(const int* deg, int* offs, int* cursor, int N) {
    __shared__ int part[1024];
    int t = threadIdx.x;
    int chunk = (N + 1023) >> 10;
    int start = t * chunk;
    int s = 0;
    for (int i = 0; i < chunk; i++) {
        int idx = start + i;
        if (idx < N) s += deg[idx];
    }
    part[t] = s;
    __syncthreads();
    for (int off = 1; off < 1024; off <<= 1) {
        int v = (t >= off) ? part[t - off] : 0;
        __syncthreads();
        part[t] += v;
        __syncthreads();
    }
    int run = part[t] - s;
    for (int i = 0; i < chunk; i++) {
        int idx = start + i;
        if (idx < N) {
            offs[idx] = run;
            cursor[idx] = run;
            run += deg[idx];
        }
    }
    if (t == 1023) offs[N] = part[1023];
}

__global__ void k_fill(const int* src, const int* dst, int* cursor, int* csr, int E, int N) {
    int e = blockIdx.x * blockDim.x + threadIdx.x;
    if (e < E) {
        int s = src[e], d = dst[e];
        if (s != d) {
            int pos = atomicAdd(&cursor[d], 1);
            csr[pos] = s;
        }
    } else if (e < E + N) {
        int i = e - E;
        int pos = atomicAdd(&cursor[i], 1);
        csr[pos] = i;
    }
}

// ================= fused attention+aggregation, layer 1 =================
// One wave per dst node. Phase A: online-softmax alpha into per-wave LDS.
// Phase B: aggregate h1, bias+ELU -> z, then wfold dot -> as2/ad2.

__global__ __launch_bounds__(256) void k_attn1(const int* offs, const int* csr,
                                               const float* __restrict__ h1,
                                               const float* __restrict__ as1,
                                               const float* __restrict__ ad1,
                                               const float* __restrict__ b1,
                                               const float* __restrict__ wfold,
                                               float* z, float* as2, float* ad2, int N) {
    __shared__ float al[4][512];  // 64 edges x 8 heads per wave
    __shared__ int   sc[4][64];
    __shared__ float zr[4][64];
    int w = threadIdx.x >> 6, lane = threadIdx.x & 63;
    int node = blockIdx.x * 4 + w;
    if (node >= N) return;
    int el = lane >> 3, h = lane & 7;
    int beg = offs[node], end = offs[node + 1];
    int deg = end - beg;
    float adv = ad1[node * 8 + h];
    float m = -1e30f, l = 0.f;
    for (int it = 0; it * 8 < deg; it++) {
        int j = beg + it * 8 + el;
        float e = -1e30f;
        int s = 0;
        if (j < end) {
            s = csr[j];
            float v = as1[s * 8 + h] + adv;
            e = LRELU(v);
        }
        if (it < 8) {
            al[w][it * 64 + lane] = e;  // linear: no bank conflicts
            if (h == 0 && j < end) sc[w][it * 8 + el] = s;
        }
        float nm = fmaxf(m, e);
        l = l * __expf(m - nm) + ((j < end) ? __expf(e - nm) : 0.f);
        m = nm;
    }
#pragma unroll
    for (int off = 8; off < 64; off <<= 1) {
        float m2 = __shfl_xor(m, off), l2 = __shfl_xor(l, off);
        float nm = fmaxf(m, m2);
        l = l * __expf(m - nm) + l2 * __expf(m2 - nm);
        m = nm;
    }
    float inv = 1.f / (l + 1e-16f);
    for (int it = 0; it < 8 && it * 8 < deg; it++) {
        int idx = it * 64 + lane;
        al[w][idx] = __expf(al[w][idx] - m) * inv;
    }
    // ---- phase B: lane = channel, head hb ----
    int hb = lane >> 3;
    float mB   = __shfl(m, hb);
    float invB = __shfl(inv, hb);
    float advB = __shfl(adv, hb);
    float acc = 0.f;
    for (int j = beg; j < end; j++) {
        int e0 = j - beg;
        float a;
        int s;
        if (e0 < 64) {
            a = al[w][e0 * 8 + hb];
            s = sc[w][e0];
        } else {  // overflow: recompute (deg>64 is rare)
            s = csr[j];
            float v = as1[s * 8 + hb] + advB;
            a = __expf(LRELU(v) - mB) * invB;
        }
        acc += a * h1[(size_t)s * 64 + lane];
    }
    float val = acc + b1[lane];
    float zv = val > 0.f ? val : __expf(val) - 1.f;  // ELU
    z[(size_t)node * 64 + lane] = zv;
    zr[w][lane] = zv;
    if (lane < 16) {
        int hh = lane & 7;
        const float* wf = wfold + (lane < 8 ? 0 : 512);
        float sdot = 0.f;
        for (int k = 0; k < 64; k++) sdot += zr[w][k] * wf[k * 8 + hh];
        if (lane < 8) as2[node * 8 + hh] = sdot;
        else          ad2[node * 8 + hh] = sdot;
    }
}

// ================= fused attention+aggregation+GEMM+log_softmax, layer 2 =================
// 256 threads, 4 nodes/block (proven round-0 shapes for BOTH phases).
// Phase A/B: verbatim round-0 k_attn2 per-wave attention; agg row -> LDS (al reuse).
// Phase C: verbatim round-0 k_out GEMM+log_softmax, 4 nodes, agg read from LDS.

__global__ __launch_bounds__(256) void k_attn2_out(const int* offs, const int* csr,
                                                   const float* __restrict__ zt,
                                                   const float* __restrict__ as2,
                                                   const float* __restrict__ ad2,
                                                   const float* __restrict__ W2,
                                                   const float* __restrict__ b2,
                                                   float* out, int N) {
    __shared__ float al[4][512];   // alpha, later agg rows [node][head*64+k]
    __shared__ int   sc[4][64];
    __shared__ float red[4][4];
    int w = threadIdx.x >> 6, lane = threadIdx.x & 63;
    int node = blockIdx.x * 4 + w;
    bool active = node < N;
    int el = lane >> 3, h = lane & 7;
    int beg = 0, end = 0;
    if (active) { beg = offs[node]; end = offs[node + 1]; }
    int deg = end - beg;
    float adv = active ? ad2[node * 8 + h] : 0.f;
    float m = -1e30f, l = 0.f;
    for (int it = 0; it * 8 < deg; it++) {
        int j = beg + it * 8 + el;
        float e = -1e30f;
        int s = 0;
        if (j < end) {
            s = csr[j];
            float v = as2[s * 8 + h] + adv;
            e = LRELU(v);
        }
        if (it < 8) {
            al[w][it * 64 + lane] = e;
            if (h == 0 && j < end) sc[w][it * 8 + el] = s;
        }
        float nm = fmaxf(m, e);
        l = l * __expf(m - nm) + ((j < end) ? __expf(e - nm) : 0.f);
        m = nm;
    }
#pragma unroll
    for (int off = 8; off < 64; off <<= 1) {
        float m2 = __shfl_xor(m, off), l2 = __shfl_xor(l, off);
        float nm = fmaxf(m, m2);
        l = l * __expf(m - nm) + l2 * __expf(m2 - nm);
        m = nm;
    }
    float inv = 1.f / (l + 1e-16f);
    for (int it = 0; it < 8 && it * 8 < deg; it++) {
        int idx = it * 64 + lane;
        al[w][idx] = __expf(al[w][idx] - m) * inv;
    }
    float mH[8], invH[8], advH[8];
#pragma unroll
    for (int hh = 0; hh < 8; hh++) {
        mH[hh] = __shfl(m, hh);
        invH[hh] = __shfl(inv, hh);
        advH[hh] = __shfl(adv, hh);
    }
    float acc[8] = {0.f, 0.f, 0.f, 0.f, 0.f, 0.f, 0.f, 0.f};
    for (int j = beg; j < end; j++) {
        int e0 = j - beg;
        float a[8];
        int s;
        if (e0 < 64) {
            float4 a0 = *(const float4*)&al[w][e0 * 8];
            float4 a1 = *(const float4*)&al[w][e0 * 8 + 4];
            a[0] = a0.x; a[1] = a0.y; a[2] = a0.z; a[3] = a0.w;
            a[4] = a1.x; a[5] = a1.y; a[6] = a1.z; a[7] = a1.w;
            s = sc[w][e0];
        } else {
            s = csr[j];
#pragma unroll
            for (int hh = 0; hh < 8; hh++) {
                float v = as2[s * 8 + hh] + advH[hh];
                a[hh] = __expf(LRELU(v) - mH[hh]) * invH[hh];
            }
        }
        float zvv = zt[(size_t)s * 64 + lane];
#pragma unroll
        for (int hh = 0; hh < 8; hh++) acc[hh] += a[hh] * zvv;
    }
    // ---- drop agg row into LDS (per-wave in-order: al[w] reads are done) ----
#pragma unroll
    for (int hh = 0; hh < 8; hh++) al[w][hh * 64 + lane] = acc[hh];
    __syncthreads();
    // ---- phase C: k_out shape, 4 nodes. thread t -> cols [t*4, t*4+4), hh = t>>5 ----
    int t = threadIdx.x;
    int c0 = t * 4;
    int hh2 = t >> 5;
    float4 acc4[4];
    float4 bb = *(const float4*)&b2[c0];
#pragma unroll
    for (int mi = 0; mi < 4; mi++) acc4[mi] = bb;
    for (int k0 = 0; k0 < 64; k0 += 4) {
        float4 w0 = *(const float4*)&W2[(size_t)(k0 + 0) * 1024 + c0];
        float4 w1 = *(const float4*)&W2[(size_t)(k0 + 1) * 1024 + c0];
        float4 w2 = *(const float4*)&W2[(size_t)(k0 + 2) * 1024 + c0];
        float4 w3 = *(const float4*)&W2[(size_t)(k0 + 3) * 1024 + c0];
#pragma unroll
        for (int mi = 0; mi < 4; mi++) {
            float4 a = *(const float4*)&al[mi][hh2 * 64 + k0];  // 2-addr broadcast
            acc4[mi].x += a.x * w0.x + a.y * w1.x + a.z * w2.x + a.w * w3.x;
            acc4[mi].y += a.x * w0.y + a.y * w1.y + a.z * w2.y + a.w * w3.y;
            acc4[mi].z += a.x * w0.z + a.y * w1.z + a.z * w2.z + a.w * w3.z;
            acc4[mi].w += a.x * w0.w + a.y * w1.w + a.z * w2.w + a.w * w3.w;
        }
    }
    float gmax[4], logZ[4];
#pragma unroll
    for (int mi = 0; mi < 4; mi++) {
        float v = fmaxf(fmaxf(acc4[mi].x, acc4[mi].y), fmaxf(acc4[mi].z, acc4[mi].w));
#pragma unroll
        for (int off = 32; off; off >>= 1) v = fmaxf(v, __shfl_xor(v, off));
        if (lane == 0) red[w][mi] = v;
    }
    __syncthreads();
#pragma unroll
    for (int mi = 0; mi < 4; mi++)
        gmax[mi] = fmaxf(fmaxf(red[0][mi], red[1][mi]), fmaxf(red[2][mi], red[3][mi]));
    __syncthreads();
#pragma unroll
    for (int mi = 0; mi < 4; mi++) {
        float v = __expf(acc4[mi].x - gmax[mi]) + __expf(acc4[mi].y - gmax[mi]) +
                  __expf(acc4[mi].z - gmax[mi]) + __expf(acc4[mi].w - gmax[mi]);
#pragma unroll
        for (int off = 32; off; off >>= 1) v += __shfl_xor(v, off);
        if (lane == 0) red[w][mi] = v;
    }
    __syncthreads();
#pragma unroll
    for (int mi = 0; mi < 4; mi++) {
        float gs = red[0][mi] + red[1][mi] + red[2][mi] + red[3][mi];
        logZ[mi] = gmax[mi] + __logf(gs);
    }
#pragma unroll
    for (int mi = 0; mi < 4; mi++) {
        int n = blockIdx.x * 4 + mi;
        if (n >= N) continue;
        float4 o;
        o.x = acc4[mi].x - logZ[mi];
        o.y = acc4[mi].y - logZ[mi];
        o.z = acc4[mi].z - logZ[mi];
        o.w = acc4[mi].w - logZ[mi];
        *(float4*)&out[(size_t)n * 1024 + c0] = o;
    }
}

// ================= launch =================

extern "C" void kernel_launch(void* const* d_in, const int* in_sizes, int n_in,
                              void* d_out, int out_size, void* d_ws, size_t ws_size,
                              hipStream_t stream) {
    const float* x      = (const float*)d_in[0];
    const int*   ei     = (const int*)d_in[1];
    const float* W1     = (const float*)d_in[2];
    const float* a_src1 = (const float*)d_in[3];
    const float* a_dst1 = (const float*)d_in[4];
    const float* b1     = (const float*)d_in[5];
    const float* W2     = (const float*)d_in[6];
    const float* a_src2 = (const float*)d_in[7];
    const float* a_dst2 = (const float*)d_in[8];
    const float* b2     = (const float*)d_in[9];
    float* out = (float*)d_out;

    int N = in_sizes[0] / 128;
    int E = in_sizes[1] / 2;
    const int* src = ei;
    const int* dst = ei + E;

    char* p = (char*)d_ws;
    auto carve = [&](size_t bytes) {
        void* r = (void*)p;
        p += (bytes + 255) & ~(size_t)255;
        return r;
    };
    int*   deg    = (int*)carve((size_t)N * 4);
    int*   offs   = (int*)carve((size_t)(N + 1) * 4);
    int*   cursor = (int*)carve((size_t)N * 4);
    int*   csr    = (int*)carve((size_t)(E + N) * 4);
    float* h1     = (float*)carve((size_t)N * 64 * 4);
    float* as1    = (float*)carve((size_t)N * 8 * 4);
    float* ad1    = (float*)carve((size_t)N * 8 * 4);
    float* z      = (float*)carve((size_t)N * 64 * 4);
    float* as2    = (float*)carve((size_t)N * 8 * 4);
    float* ad2    = (float*)carve((size_t)N * 8 * 4);
    float* wfold  = (float*)carve((size_t)1024 * 4);

    int GB = (N + 15) / 16;                 // gemm1 blocks
    int DB = (N + 255) / 256;               // deg-init blocks
    int nb4 = (N + 3) / 4;

    // K1: gemm1 + fold + deg-init (independent work, one dispatch)
    k_front<<<GB + 64 + DB, 256, 0, stream>>>(x, W1, a_src1, a_dst1, W2, a_src2, a_dst2,
                                              h1, as1, ad1, wfold, deg, N, GB);
    // CSR build
    k_hist<<<(E + 255) / 256, 256, 0, stream>>>(src, dst, deg, E);
    k_scan<<<1, 1024, 0, stream>>>(deg, offs, cursor, N);
    k_fill<<<(E + N + 255) / 256, 256, 0, stream>>>(src, dst, cursor, csr, E, N);
    // layer 1 (fused alpha+agg)
    k_attn1<<<nb4, 256, 0, stream>>>(offs, csr, h1, as1, ad1, b1, wfold, z, as2, ad2, N);
    // layer 2 (fused alpha+agg+GEMM+log_softmax) — no agg round-trip, 256-thr proven shape
    k_attn2_out<<<nb4, 256, 0, stream>>>(offs, csr, z, as2, ad2, W2, b2, out, N);
}

// Round 3
// 233.140 us; speedup vs baseline: 2.4230x; 1.6920x over previous
//
#include <hip/hip_runtime.h>
#include <cstddef>
#include <cstdint>

#define LRELU(v) ((v) > 0.f ? (v) : 0.2f * (v))

// ================= K1: fused gemm1 + fold(W2,a2) + deg-init =================
// blocks [0,GB): h1 = x@W1 (+as1/ad1);  [GB,GB+64): wfold;  rest: deg[i]=1.

__global__ __launch_bounds__(256) void k_front(const float* __restrict__ x,
                                               const float* __restrict__ W1,
                                               const float* __restrict__ a_src1,
                                               const float* __restrict__ a_dst1,
                                               const float* __restrict__ W2,
                                               const float* __restrict__ a_src2,
                                               const float* __restrict__ a_dst2,
                                               float* h1, float* as1, float* ad1,
                                               float* wfold, int* deg, int N, int GB) {
    int t = threadIdx.x;
    int b = blockIdx.x;
    if (b < GB) {
        // ---- gemm1: 16 nodes/block, 4 waves, wave owns 4 nodes, lane = column ----
        __shared__ float xs[16][128];
        int n0 = b * 16;
#pragma unroll
        for (int i = 0; i < 2; i++) {
            int idx = (t + i * 256) * 4;
            int r = idx >> 7, c = idx & 127;
            int n = n0 + r;
            float4 v = make_float4(0.f, 0.f, 0.f, 0.f);
            if (n < N) v = *(const float4*)&x[(size_t)n * 128 + c];
            *(float4*)&xs[r][c] = v;
        }
        __syncthreads();
        int wv = t >> 6, lane = t & 63;
        int m0 = wv * 4;
        float acc[4] = {0.f, 0.f, 0.f, 0.f};
        for (int k0 = 0; k0 < 128; k0 += 4) {
            float w0 = W1[(k0 + 0) * 64 + lane];
            float w1 = W1[(k0 + 1) * 64 + lane];
            float w2 = W1[(k0 + 2) * 64 + lane];
            float w3 = W1[(k0 + 3) * 64 + lane];
#pragma unroll
            for (int mi = 0; mi < 4; mi++) {
                float4 a = *(const float4*)&xs[m0 + mi][k0];
                acc[mi] += a.x * w0 + a.y * w1 + a.z * w2 + a.w * w3;
            }
        }
        float was = a_src1[lane], wad = a_dst1[lane];
#pragma unroll
        for (int mi = 0; mi < 4; mi++) {
            int n = n0 + m0 + mi;
            if (n >= N) break;
            h1[(size_t)n * 64 + lane] = acc[mi];
            float ps = acc[mi] * was, pd = acc[mi] * wad;
            ps += __shfl_xor(ps, 1); ps += __shfl_xor(ps, 2); ps += __shfl_xor(ps, 4);
            pd += __shfl_xor(pd, 1); pd += __shfl_xor(pd, 2); pd += __shfl_xor(pd, 4);
            if ((lane & 7) == 0) {
                as1[n * 8 + (lane >> 3)] = ps;
                ad1[n * 8 + (lane >> 3)] = pd;
            }
        }
    } else if (b < GB + 64) {
        // ---- fold: block per k-row of W2; coalesced float4; 32-lane head groups ----
        int k = b - GB;
        int c0 = t * 4;
        int h = t >> 5;
        float4 w = *(const float4*)&W2[(size_t)k * 1024 + c0];
        float4 s4 = *(const float4*)&a_src2[c0];
        float4 d4 = *(const float4*)&a_dst2[c0];
        float ss = w.x * s4.x + w.y * s4.y + w.z * s4.z + w.w * s4.w;
        float sd = w.x * d4.x + w.y * d4.y + w.z * d4.z + w.w * d4.w;
#pragma unroll
        for (int off = 1; off <= 16; off <<= 1) {
            ss += __shfl_xor(ss, off);
            sd += __shfl_xor(sd, off);
        }
        if ((t & 31) == 0) {
            wfold[k * 8 + h] = ss;
            wfold[512 + k * 8 + h] = sd;
        }
    } else {
        int i = (b - GB - 64) * 256 + t;
        if (i < N) deg[i] = 1;  // self-loop
    }
}

// ================= CSR build =================

__global__ void k_hist(const int* src, const int* dst, int* deg, int E) {
    int e = blockIdx.x * blockDim.x + threadIdx.x;
    if (e < E) {
        int s = src[e], d = dst[e];
        if (s != d) atomicAdd(&deg[d], 1);
    }
}

__global__ __launch_bounds__(1024) void k_scan(const int* deg, int* offs, int* cursor, int N) {
    __shared__ int part[1024];
    int t = threadIdx.x;
    int chunk = (N + 1023) >> 10;
    int start = t * chunk;
    int s = 0;
    for (int i = 0; i < chunk; i++) {
        int idx = start + i;
        if (idx < N) s += deg[idx];
    }
    part[t] = s;
    __syncthreads();
    for (int off = 1; off < 1024; off <<= 1) {
        int v = (t >= off) ? part[t - off] : 0;
        __syncthreads();
        part[t] += v;
        __syncthreads();
    }
    int run = part[t] - s;
    for (int i = 0; i < chunk; i++) {
        int idx = start + i;
        if (idx < N) {
            offs[idx] = run;
            cursor[idx] = run;
            run += deg[idx];
        }
    }
    if (t == 1023) offs[N] = part[1023];
}

__global__ void k_fill(const int* src, const int* dst, int* cursor, int* csr, int E, int N) {
    int e = blockIdx.x * blockDim.x + threadIdx.x;
    if (e < E) {
        int s = src[e], d = dst[e];
        if (s != d) {
            int pos = atomicAdd(&cursor[d], 1);
            csr[pos] = s;
        }
    } else if (e < E + N) {
        int i = e - E;
        int pos = atomicAdd(&cursor[i], 1);
        csr[pos] = i;
    }
}

// ================= fused attention+aggregation, layer 1 =================
// One wave per dst node. Phase A: online-softmax alpha into per-wave LDS.
// Phase B: aggregate h1, bias+ELU -> z, then wfold dot -> as2/ad2.

__global__ __launch_bounds__(256) void k_attn1(const int* offs, const int* csr,
                                               const float* __restrict__ h1,
                                               const float* __restrict__ as1,
                                               const float* __restrict__ ad1,
                                               const float* __restrict__ b1,
                                               const float* __restrict__ wfold,
                                               float* z, float* as2, float* ad2, int N) {
    __shared__ float al[4][512];  // 64 edges x 8 heads per wave
    __shared__ int   sc[4][64];
    __shared__ float zr[4][64];
    int w = threadIdx.x >> 6, lane = threadIdx.x & 63;
    int node = blockIdx.x * 4 + w;
    if (node >= N) return;
    int el = lane >> 3, h = lane & 7;
    int beg = offs[node], end = offs[node + 1];
    int deg = end - beg;
    float adv = ad1[node * 8 + h];
    float m = -1e30f, l = 0.f;
    for (int it = 0; it * 8 < deg; it++) {
        int j = beg + it * 8 + el;
        float e = -1e30f;
        int s = 0;
        if (j < end) {
            s = csr[j];
            float v = as1[s * 8 + h] + adv;
            e = LRELU(v);
        }
        if (it < 8) {
            al[w][it * 64 + lane] = e;  // linear: no bank conflicts
            if (h == 0 && j < end) sc[w][it * 8 + el] = s;
        }
        float nm = fmaxf(m, e);
        l = l * __expf(m - nm) + ((j < end) ? __expf(e - nm) : 0.f);
        m = nm;
    }
#pragma unroll
    for (int off = 8; off < 64; off <<= 1) {
        float m2 = __shfl_xor(m, off), l2 = __shfl_xor(l, off);
        float nm = fmaxf(m, m2);
        l = l * __expf(m - nm) + l2 * __expf(m2 - nm);
        m = nm;
    }
    float inv = 1.f / (l + 1e-16f);
    for (int it = 0; it < 8 && it * 8 < deg; it++) {
        int idx = it * 64 + lane;
        al[w][idx] = __expf(al[w][idx] - m) * inv;
    }
    // ---- phase B: lane = channel, head hb ----
    int hb = lane >> 3;
    float acc = 0.f;
    for (int j = beg; j < end; j++) {
        int e0 = j - beg;
        float a;
        int s;
        if (e0 < 64) {               // wave-uniform branch (hot: deg<=64 always here)
            a = al[w][e0 * 8 + hb];
            s = sc[w][e0];
        } else {                     // cold overflow: shuffles kept branch-local (VGPR)
            float mB   = __shfl(m, hb);
            float invB = __shfl(inv, hb);
            float advB = __shfl(adv, hb);
            s = csr[j];
            float v = as1[s * 8 + hb] + advB;
            a = __expf(LRELU(v) - mB) * invB;
        }
        acc += a * h1[(size_t)s * 64 + lane];
    }
    float val = acc + b1[lane];
    float zv = val > 0.f ? val : __expf(val) - 1.f;  // ELU
    z[(size_t)node * 64 + lane] = zv;
    zr[w][lane] = zv;
    if (lane < 16) {
        int hh = lane & 7;
        const float* wf = wfold + (lane < 8 ? 0 : 512);
        float sdot = 0.f;
        for (int k = 0; k < 64; k++) sdot += zr[w][k] * wf[k * 8 + hh];
        if (lane < 8) as2[node * 8 + hh] = sdot;
        else          ad2[node * 8 + hh] = sdot;
    }
}

// ================= fused attention+aggregation, layer 2 =================
// Phase B: lane = channel (64), all 8 heads accumulated -> agg[N,8,64].

__global__ __launch_bounds__(256) void k_attn2(const int* offs, const int* csr,
                                               const float* __restrict__ zt,
                                               const float* __restrict__ as2,
                                               const float* __restrict__ ad2,
                                               float* agg, int N) {
    __shared__ float al[4][512];
    __shared__ int   sc[4][64];
    int w = threadIdx.x >> 6, lane = threadIdx.x & 63;
    int node = blockIdx.x * 4 + w;
    if (node >= N) return;
    int el = lane >> 3, h = lane & 7;
    int beg = offs[node], end = offs[node + 1];
    int deg = end - beg;
    float adv = ad2[node * 8 + h];
    float m = -1e30f, l = 0.f;
    for (int it = 0; it * 8 < deg; it++) {
        int j = beg + it * 8 + el;
        float e = -1e30f;
        int s = 0;
        if (j < end) {
            s = csr[j];
            float v = as2[s * 8 + h] + adv;
            e = LRELU(v);
        }
        if (it < 8) {
            al[w][it * 64 + lane] = e;
            if (h == 0 && j < end) sc[w][it * 8 + el] = s;
        }
        float nm = fmaxf(m, e);
        l = l * __expf(m - nm) + ((j < end) ? __expf(e - nm) : 0.f);
        m = nm;
    }
#pragma unroll
    for (int off = 8; off < 64; off <<= 1) {
        float m2 = __shfl_xor(m, off), l2 = __shfl_xor(l, off);
        float nm = fmaxf(m, m2);
        l = l * __expf(m - nm) + l2 * __expf(m2 - nm);
        m = nm;
    }
    float inv = 1.f / (l + 1e-16f);
    for (int it = 0; it < 8 && it * 8 < deg; it++) {
        int idx = it * 64 + lane;
        al[w][idx] = __expf(al[w][idx] - m) * inv;
    }
    float acc[8] = {0.f, 0.f, 0.f, 0.f, 0.f, 0.f, 0.f, 0.f};
    for (int j = beg; j < end; j++) {
        int e0 = j - beg;
        float a[8];
        int s;
        if (e0 < 64) {               // wave-uniform branch (hot: deg<=64 always here)
            float4 a0 = *(const float4*)&al[w][e0 * 8];
            float4 a1 = *(const float4*)&al[w][e0 * 8 + 4];
            a[0] = a0.x; a[1] = a0.y; a[2] = a0.z; a[3] = a0.w;
            a[4] = a1.x; a[5] = a1.y; a[6] = a1.z; a[7] = a1.w;
            s = sc[w][e0];
        } else {                     // cold overflow: shuffles branch-local (saves ~24 VGPR)
            s = csr[j];
#pragma unroll
            for (int hh = 0; hh < 8; hh++) {
                float mHh   = __shfl(m, hh);
                float invHh = __shfl(inv, hh);
                float advHh = __shfl(adv, hh);
                float v = as2[s * 8 + hh] + advHh;
                a[hh] = __expf(LRELU(v) - mHh) * invHh;
            }
        }
        float zvv = zt[(size_t)s * 64 + lane];
#pragma unroll
        for (int hh = 0; hh < 8; hh++) acc[hh] += a[hh] * zvv;
    }
#pragma unroll
    for (int hh = 0; hh < 8; hh++)
        agg[(size_t)node * 512 + hh * 64 + lane] = acc[hh];
}

// ================= final per-head GEMM + bias + log_softmax =================

__global__ __launch_bounds__(256) void k_out(const float* __restrict__ agg,
                                             const float* __restrict__ W2,
                                             const float* __restrict__ b2,
                                             float* out, int N) {
    __shared__ float sa[4096];
    __shared__ float red[4][8];
    int t = threadIdx.x;
    int n0 = blockIdx.x * 8;
#pragma unroll
    for (int i = 0; i < 4; i++) {
        int idx = (t + i * 256) * 4;
        int r = idx >> 9, c = idx & 511;
        int n = n0 + r;
        float4 v = make_float4(0.f, 0.f, 0.f, 0.f);
        if (n < N) v = *(const float4*)&agg[(size_t)n * 512 + c];
        *(float4*)&sa[idx] = v;
    }
    __syncthreads();
    int c0 = t * 4;
    int hh = t >> 5;
    float4 acc[8];
    float4 bb = *(const float4*)&b2[c0];
#pragma unroll
    for (int mi = 0; mi < 8; mi++) acc[mi] = bb;
    for (int k0 = 0; k0 < 64; k0 += 4) {
        float4 w0 = *(const float4*)&W2[(size_t)(k0 + 0) * 1024 + c0];
        float4 w1 = *(const float4*)&W2[(size_t)(k0 + 1) * 1024 + c0];
        float4 w2 = *(const float4*)&W2[(size_t)(k0 + 2) * 1024 + c0];
        float4 w3 = *(const float4*)&W2[(size_t)(k0 + 3) * 1024 + c0];
#pragma unroll
        for (int mi = 0; mi < 8; mi++) {
            float4 a = *(const float4*)&sa[mi * 512 + hh * 64 + k0];
            acc[mi].x += a.x * w0.x + a.y * w1.x + a.z * w2.x + a.w * w3.x;
            acc[mi].y += a.x * w0.y + a.y * w1.y + a.z * w2.y + a.w * w3.y;
            acc[mi].z += a.x * w0.z + a.y * w1.z + a.z * w2.z + a.w * w3.z;
            acc[mi].w += a.x * w0.w + a.y * w1.w + a.z * w2.w + a.w * w3.w;
        }
    }
    int wave = t >> 6, lane = t & 63;
    float gmax[8], logZ[8];
#pragma unroll
    for (int mi = 0; mi < 8; mi++) {
        float v = fmaxf(fmaxf(acc[mi].x, acc[mi].y), fmaxf(acc[mi].z, acc[mi].w));
        for (int off = 32; off; off >>= 1) v = fmaxf(v, __shfl_xor(v, off));
        if (lane == 0) red[wave][mi] = v;
    }
    __syncthreads();
#pragma unroll
    for (int mi = 0; mi < 8; mi++)
        gmax[mi] = fmaxf(fmaxf(red[0][mi], red[1][mi]), fmaxf(red[2][mi], red[3][mi]));
    __syncthreads();
#pragma unroll
    for (int mi = 0; mi < 8; mi++) {
        float v = __expf(acc[mi].x - gmax[mi]) + __expf(acc[mi].y - gmax[mi]) +
                  __expf(acc[mi].z - gmax[mi]) + __expf(acc[mi].w - gmax[mi]);
        for (int off = 32; off; off >>= 1) v += __shfl_xor(v, off);
        if (lane == 0) red[wave][mi] = v;
    }
    __syncthreads();
#pragma unroll
    for (int mi = 0; mi < 8; mi++) {
        float gs = red[0][mi] + red[1][mi] + red[2][mi] + red[3][mi];
        logZ[mi] = gmax[mi] + __logf(gs);
    }
#pragma unroll
    for (int mi = 0; mi < 8; mi++) {
        int n = n0 + mi;
        if (n >= N) continue;
        float4 o;
        o.x = acc[mi].x - logZ[mi];
        o.y = acc[mi].y - logZ[mi];
        o.z = acc[mi].z - logZ[mi];
        o.w = acc[mi].w - logZ[mi];
        *(float4*)&out[(size_t)n * 1024 + c0] = o;
    }
}

// ================= launch =================

extern "C" void kernel_launch(void* const* d_in, const int* in_sizes, int n_in,
                              void* d_out, int out_size, void* d_ws, size_t ws_size,
                              hipStream_t stream) {
    const float* x      = (const float*)d_in[0];
    const int*   ei     = (const int*)d_in[1];
    const float* W1     = (const float*)d_in[2];
    const float* a_src1 = (const float*)d_in[3];
    const float* a_dst1 = (const float*)d_in[4];
    const float* b1     = (const float*)d_in[5];
    const float* W2     = (const float*)d_in[6];
    const float* a_src2 = (const float*)d_in[7];
    const float* a_dst2 = (const float*)d_in[8];
    const float* b2     = (const float*)d_in[9];
    float* out = (float*)d_out;

    int N = in_sizes[0] / 128;
    int E = in_sizes[1] / 2;
    const int* src = ei;
    const int* dst = ei + E;

    char* p = (char*)d_ws;
    auto carve = [&](size_t bytes) {
        void* r = (void*)p;
        p += (bytes + 255) & ~(size_t)255;
        return r;
    };
    int*   deg    = (int*)carve((size_t)N * 4);
    int*   offs   = (int*)carve((size_t)(N + 1) * 4);
    int*   cursor = (int*)carve((size_t)N * 4);
    int*   csr    = (int*)carve((size_t)(E + N) * 4);
    float* h1     = (float*)carve((size_t)N * 64 * 4);
    float* as1    = (float*)carve((size_t)N * 8 * 4);
    float* ad1    = (float*)carve((size_t)N * 8 * 4);
    float* z      = (float*)carve((size_t)N * 64 * 4);
    float* as2    = (float*)carve((size_t)N * 8 * 4);
    float* ad2    = (float*)carve((size_t)N * 8 * 4);
    float* wfold  = (float*)carve((size_t)1024 * 4);
    float* agg    = (float*)carve((size_t)N * 512 * 4);

    int GB = (N + 15) / 16;                 // gemm1 blocks
    int DB = (N + 255) / 256;               // deg-init blocks
    int nb4 = (N + 3) / 4;

    // K1: gemm1 + fold + deg-init (independent work, one dispatch)
    k_front<<<GB + 64 + DB, 256, 0, stream>>>(x, W1, a_src1, a_dst1, W2, a_src2, a_dst2,
                                              h1, as1, ad1, wfold, deg, N, GB);
    // CSR build
    k_hist<<<(E + 255) / 256, 256, 0, stream>>>(src, dst, deg, E);
    k_scan<<<1, 1024, 0, stream>>>(deg, offs, cursor, N);
    k_fill<<<(E + N + 255) / 256, 256, 0, stream>>>(src, dst, cursor, csr, E, N);
    // layer 1 (fused alpha+agg)
    k_attn1<<<nb4, 256, 0, stream>>>(offs, csr, h1, as1, ad1, b1, wfold, z, as2, ad2, N);
    // layer 2 (fused alpha+agg)
    k_attn2<<<nb4, 256, 0, stream>>>(offs, csr, z, as2, ad2, agg, N);
    // output GEMM + log_softmax
    k_out<<<(N + 7) / 8, 256, 0, stream>>>(agg, W2, b2, out, N);
}